// Round 1
// baseline (98.563 us; speedup 1.0000x reference)
//
#include <hip/hip_runtime.h>
#include <math.h>

#define BB   8
#define NN   96
#define DD   16
#define H0D  50
#define H1D  50
#define OUTD 64
#define XP   17
#define GPB  12            // blocks (i-slices) per batch
#define SZ   (NN / GPB)    // 8 output rows per block
#define NW   8             // waves per block (== SZ: one i per wave)
#define NT   (NW * 64)

typedef unsigned long long u64;

// W1: (51,50): rows 0-15 Wxi, 16-31 Wxj, 32-47 Wxk, 48 w_ij, 49 w_jk, 50 w_ik
// W2: (83,50): rows 0-15 xi, 16-31 xj, 32 dis, 33-82 m3
// W3: (66,64)

__global__ __launch_bounds__(NT) void kfused(
    const float* __restrict__ x, const float* __restrict__ adj,
    const float* __restrict__ W1, const float* __restrict__ b1,
    const float* __restrict__ W2, const float* __restrict__ b2,
    const float* __restrict__ W3, const float* __restrict__ b3,
    float* __restrict__ out)
{
    const int b   = blockIdx.x / GPB;
    const int s0  = (blockIdx.x % GPB) * SZ;
    const int tid = threadIdx.x;
    const int w   = tid >> 6, lane = tid & 63;

    __shared__ float sx[NN * XP];            // x batch, padded rows
    __shared__ float sdis[SZ][NN + 1];       // dis rows for this block's i's
    __shared__ u64   sm0[NN], sm1[NN];       // adjacency bitmasks per j
    __shared__ float sdeg[NN], ssdjk[NN];
    __shared__ float snx[NN][DD];            // sum_{k in nbr(j)} x_k
    __shared__ float sP[NN][H0D + 2];        // deg_j*Bm_j + sumC_j

    // ---- stage x[b] (one float4 per thread) --------------------------------
    const float4* x4 = (const float4*)(x + (size_t)b * NN * DD);
    if (tid < NN * DD / 4) {
        float4 v = x4[tid];
        int row = tid >> 2, d = (tid & 3) * 4;
        float* p = &sx[row * XP + d];
        p[0] = v.x; p[1] = v.y; p[2] = v.z; p[3] = v.w;
    }
    __syncthreads();

    const int h = (lane < H0D) ? lane : 0;

    // W1 panels for phase A in registers (lane = channel h)
    float wB[DD], wC[DD];
    #pragma unroll
    for (int d = 0; d < DD; ++d) {
        wB[d] = W1[(DD + d) * H0D + h];
        wC[d] = W1[(2 * DD + d) * H0D + h];
    }

    // ---- phase A: per-j quantities, 12 rows per wave -----------------------
    for (int j = w; j < NN; j += NW) {
        const float* arow = adj + ((size_t)b * NN + j) * NN;
        float a0 = arow[lane];
        float a1 = (lane < NN - 64) ? arow[64 + lane] : 0.f;
        u64 m0 = __ballot(a0 != 0.f);
        u64 m1 = __ballot(a1 != 0.f);
        float deg = (float)(__popcll(m0) + __popcll(m1));

        // dis row j (lane = k, two rounds)
        const float* xj = &sx[j * XP];
        float d0, d1 = 0.f;
        {
            float s = 1e-10f;
            const float* xk = &sx[lane * XP];
            #pragma unroll
            for (int d = 0; d < DD; ++d) { float t = xj[d] - xk[d]; s += t * t; }
            d0 = sqrtf(s);
        }
        if (lane < NN - 64) {
            float s = 1e-10f;
            const float* xk = &sx[(64 + lane) * XP];
            #pragma unroll
            for (int d = 0; d < DD; ++d) { float t = xj[d] - xk[d]; s += t * t; }
            d1 = sqrtf(s);
        }
        if (j >= s0 && j < s0 + SZ) {
            sdis[j - s0][lane] = d0;
            if (lane < NN - 64) sdis[j - s0][64 + lane] = d1;
        }

        // sd_jk[j] = sum_{k in nbr(j)} dis[j,k]
        float part = (((m0 >> lane) & 1) ? d0 : 0.f)
                   + ((lane < 32 && ((m1 >> lane) & 1)) ? d1 : 0.f);
        #pragma unroll
        for (int off = 1; off < 64; off <<= 1) part += __shfl_xor(part, off, 64);
        if (lane == 0) {
            sm0[j] = m0; sm1[j] = m1; sdeg[j] = deg; ssdjk[j] = part;
        }

        // nx_j[d] = sum_{k in nbr(j)} x_k[d]; lane = d + 16*chunk (4 chunks of 24 k)
        int c = lane >> 4, d = lane & 15;
        unsigned sm;
        if (c == 0)      sm = (unsigned)(m0 & 0xFFFFFFu);
        else if (c == 1) sm = (unsigned)((m0 >> 24) & 0xFFFFFFu);
        else if (c == 2) sm = (unsigned)((m0 >> 48) & 0xFFFFu) | ((unsigned)(m1 & 0xFFu) << 16);
        else             sm = (unsigned)((m1 >> 8) & 0xFFFFFFu);
        float nxv = 0.f;
        int base = c * 24;
        while (sm) {
            int k = base + __ffs(sm) - 1;
            sm &= sm - 1;
            nxv += sx[k * XP + d];
        }
        nxv += __shfl_xor(nxv, 16, 64);
        nxv += __shfl_xor(nxv, 32, 64);   // now every lane holds nx_j[lane & 15]
        if (lane < DD) snx[j][lane] = nxv;

        // P_j[h] = deg_j * (x_j @ Wxj)[h] + (nx_j @ Wxk)[h]  (cross-lane via shfl)
        float p = 0.f, bm = 0.f;
        #pragma unroll
        for (int d2 = 0; d2 < DD; ++d2) {
            bm += sx[j * XP + d2] * wB[d2];
            p  += __shfl(nxv, d2, 64) * wC[d2];
        }
        if (lane < H0D) sP[j][lane] = deg * bm + p;
    }
    __syncthreads();

    // ---- phase B: one output row i per wave --------------------------------
    const int i  = s0 + w;
    const int il = w;   // SZ == NW

    // sd_ik[i,j] in registers: lane j (and j+64 for lane<32)
    float sdik0 = 0.f, sdik1 = 0.f;
    {
        u64 mm0 = sm0[lane], mm1 = sm1[lane];
        while (mm0) { int k = __ffsll(mm0) - 1;      mm0 &= mm0 - 1; sdik0 += sdis[il][k]; }
        while (mm1) { int k = 64 + __ffsll(mm1) - 1; mm1 &= mm1 - 1; sdik0 += sdis[il][k]; }
    }
    if (lane < NN - 64) {
        int j1 = 64 + lane;
        u64 mm0 = sm0[j1], mm1 = sm1[j1];
        while (mm0) { int k = __ffsll(mm0) - 1;      mm0 &= mm0 - 1; sdik1 += sdis[il][k]; }
        while (mm1) { int k = 64 + __ffsll(mm1) - 1; mm1 &= mm1 - 1; sdik1 += sdis[il][k]; }
    }

    // neighbor accumulation (lane = channel h), wave-uniform mask walk
    float wA[DD];
    #pragma unroll
    for (int d = 0; d < DD; ++d) wA[d] = W1[d * H0D + h];
    const float wij = W1[(3 * DD + 0) * H0D + h];
    const float wjk = W1[(3 * DD + 1) * H0D + h];
    const float wik = W1[(3 * DD + 2) * H0D + h];

    float ab = b1[h];
    #pragma unroll
    for (int d = 0; d < DD; ++d) ab += sx[i * XP + d] * wA[d];

    float msum = 0.f;
    {
        u64 mm = sm0[i]; int base = 0;
        for (int half = 0; half < 2; ++half) {
            while (mm) {
                int j = base + __ffsll(mm) - 1;
                mm &= mm - 1;
                float sdikj = (j < 64) ? __shfl(sdik0, j, 64)
                                       : __shfl(sdik1, j - 64, 64);
                float S = sdeg[j] * (ab + sdis[il][j] * wij) + sP[j][h]
                        + ssdjk[j] * wjk + sdikj * wik;
                msum += (S >= 0.f) ? S : 0.05f * S;
            }
            mm = sm1[i]; base = 64;
        }
    }

    // layer 2 (lane = channel, msum broadcast via shfl)
    const float degi = sdeg[i], sdjki = ssdjk[i];
    float s2 = degi * b2[h];
    #pragma unroll
    for (int d = 0; d < DD; ++d)
        s2 += degi * sx[i * XP + d] * W2[d * H1D + h]
            + snx[i][d] * W2[(DD + d) * H1D + h];
    s2 += sdjki * W2[(2 * DD) * H1D + h];
    for (int c = 0; c < H0D; ++c)
        s2 += __shfl(msum, c, 64) * W2[(2 * DD + 1 + c) * H1D + h];
    float m2v = (s2 >= 0.f) ? s2 : 0.05f * s2;

    // layer 3 + store (lane = output channel)
    float s3 = b3[lane];
    #pragma unroll
    for (int d = 0; d < DD; ++d) s3 += sx[i * XP + d] * W3[d * OUTD + lane];
    for (int c = 0; c < H1D; ++c) s3 += __shfl(m2v, c, 64) * W3[(DD + c) * OUTD + lane];
    s3 = (s3 >= 0.f) ? s3 : 0.05f * s3;
    out[((size_t)b * NN + i) * OUTD + lane] = s3;
}

extern "C" void kernel_launch(void* const* d_in, const int* in_sizes, int n_in,
                              void* d_out, int out_size, void* d_ws, size_t ws_size,
                              hipStream_t stream) {
    const float* x   = (const float*)d_in[0];
    const float* adj = (const float*)d_in[1];
    const float* W1  = (const float*)d_in[2];
    const float* b1  = (const float*)d_in[3];
    const float* W2  = (const float*)d_in[4];
    const float* b2  = (const float*)d_in[5];
    const float* W3  = (const float*)d_in[6];
    const float* b3  = (const float*)d_in[7];
    float* out = (float*)d_out;
    (void)d_ws; (void)ws_size;   // no workspace: everything lives in LDS/registers

    kfused<<<BB * GPB, NT, 0, stream>>>(x, adj, W1, b1, W2, b2, W3, b3, out);
}

// Round 2
// 79.374 us; speedup vs baseline: 1.2418x; 1.2418x over previous
//
#include <hip/hip_runtime.h>
#include <math.h>

#define BB   8
#define NN   96
#define DD   16
#define H0D  50
#define H1D  50
#define OUTD 64
#define XP   17

typedef unsigned long long u64;

// W1: (51,50): rows 0-15 Wxi, 16-31 Wxj, 32-47 Wxk, 48 w_ij, 49 w_jk, 50 w_ik
// W2: (83,50): rows 0-15 xi, 16-31 xj, 32 dis, 33-82 m3
// W3: (66,64)

__device__ __forceinline__ float wave_reduce_sum(float v) {
    #pragma unroll
    for (int off = 1; off < 64; off <<= 1)
        v += __shfl_xor(v, off, 64);
    return v;
}

// ---- kernel A: one wave per (b, j) -----------------------------------------
__global__ __launch_bounds__(64) void kA(
    const float* __restrict__ x, const float* __restrict__ adj,
    const float* __restrict__ W1,
    float* __restrict__ disws, u64* __restrict__ maskws,
    float* __restrict__ degws, float* __restrict__ sdjkws,
    float* __restrict__ nxws, float* __restrict__ APws)
{
    const int b = blockIdx.x / NN, j = blockIdx.x % NN;
    const int lane = threadIdx.x;
    __shared__ float sx[NN * XP];
    __shared__ float sar[NN];     // adj row j as float (exactly 0/1)
    __shared__ float snx[DD];

    // stage x[b] (float4, coalesced)
    const float4* x4 = (const float4*)(x + (size_t)b * NN * DD);
    #pragma unroll
    for (int t = lane; t < NN * DD / 4; t += 64) {
        float4 v = x4[t];
        int row = t >> 2, d = (t & 3) * 4;
        float* p = &sx[row * XP + d];
        p[0] = v.x; p[1] = v.y; p[2] = v.z; p[3] = v.w;
    }
    // adjacency row j + bitmask
    const float* arow = adj + ((size_t)b * NN + j) * NN;
    float a0 = arow[lane];
    float a1 = (lane < NN - 64) ? arow[64 + lane] : 0.f;
    u64 m0 = __ballot(a0 != 0.f);
    u64 m1 = __ballot(a1 != 0.f);
    sar[lane] = a0;
    if (lane < NN - 64) sar[64 + lane] = a1;
    __syncthreads();

    // dis row j (lane = k, two rounds)
    const float* xj = &sx[j * XP];
    float d0, d1 = 0.f;
    {
        float s = 1e-10f;
        const float* xk = &sx[lane * XP];
        #pragma unroll
        for (int d = 0; d < DD; ++d) { float t = xj[d] - xk[d]; s += t * t; }
        d0 = sqrtf(s);
    }
    if (lane < NN - 64) {
        float s = 1e-10f;
        const float* xk = &sx[(64 + lane) * XP];
        #pragma unroll
        for (int d = 0; d < DD; ++d) { float t = xj[d] - xk[d]; s += t * t; }
        d1 = sqrtf(s);
    }
    float* drow = disws + ((size_t)b * NN + j) * NN;
    drow[lane] = d0;
    if (lane < NN - 64) drow[64 + lane] = d1;

    float deg = (float)(__popcll(m0) + __popcll(m1));
    float part = (((m0 >> lane) & 1) ? d0 : 0.f)
               + ((lane < 32 && ((m1 >> lane) & 1)) ? d1 : 0.f);
    float sdjk = wave_reduce_sum(part);
    if (lane == 0) {
        degws[b * NN + j]  = deg;
        sdjkws[b * NN + j] = sdjk;
        maskws[(b * NN + j) * 2 + 0] = m0;
        maskws[(b * NN + j) * 2 + 1] = m1;
    }

    // nx_j[d] = sum_k adj[j,k]*x[k,d]; lane = d + 16*chunk, dense 24-k FMA loop
    {
        int c = lane >> 4, d = lane & 15, base = c * 24;
        float s = 0.f;
        #pragma unroll
        for (int t = 0; t < 24; ++t)
            s += sar[base + t] * sx[(base + t) * XP + d];
        s += __shfl_xor(s, 16, 64);
        s += __shfl_xor(s, 32, 64);
        if (lane < DD) {
            snx[lane] = s;
            nxws[(b * NN + j) * DD + lane] = s;
        }
    }
    __syncthreads();

    // A_j[h] = x_j@Wxi;  P_j[h] = deg_j*(x_j@Wxj)[h] + (nx_j@Wxk)[h]
    if (lane < H0D) {
        float a = 0.f, bm = 0.f, sc = 0.f;
        #pragma unroll
        for (int d = 0; d < DD; ++d) {
            float xv = xj[d];
            a  += xv * W1[d * H0D + lane];
            bm += xv * W1[(DD + d) * H0D + lane];
            sc += snx[d] * W1[(2 * DD + d) * H0D + lane];
        }
        float* ap = APws + ((size_t)b * NN + j) * 128;
        ap[lane]      = a;
        ap[64 + lane] = deg * bm + sc;
    }
}

// ---- kernel B: 4 waves per (b, i) ------------------------------------------
__global__ __launch_bounds__(256) void kB(
    const float* __restrict__ x,
    const float* __restrict__ W1, const float* __restrict__ b1,
    const float* __restrict__ W2, const float* __restrict__ b2,
    const float* __restrict__ W3, const float* __restrict__ b3,
    const float* __restrict__ disws, const u64* __restrict__ maskws,
    const float* __restrict__ degws, const float* __restrict__ sdjkws,
    const float* __restrict__ nxws, const float* __restrict__ APws,
    float* __restrict__ out)
{
    const int b = blockIdx.x / NN, i = blockIdx.x % NN;
    const int tid = threadIdx.x;
    const int w = tid >> 6, lane = tid & 63;
    __shared__ u64 sm0[NN], sm1[NN];
    __shared__ float sdis[NN], sdeg[NN], ssdjk[NN], ssdik[NN];
    __shared__ float sxi[DD], snxi[DD];
    __shared__ float smsum[4][H0D], smsumR[H0D], sm2[H1D];

    // ---- staging (spread across 256 threads, all coalesced) ----------------
    const ulonglong2* mp = (const ulonglong2*)(maskws + (size_t)b * NN * 2);
    const float* drow = disws + ((size_t)b * NN + i) * NN;
    if (tid < NN) {
        ulonglong2 m = mp[tid];
        sm0[tid] = m.x; sm1[tid] = m.y;
        sdeg[tid]  = degws[b * NN + tid];
        ssdjk[tid] = sdjkws[b * NN + tid];
    } else if (tid < 2 * NN) {
        int t = tid - NN;
        sdis[t] = drow[t];
    } else if (tid >= 224 && tid < 224 + DD) {
        sxi[tid - 224] = x[((size_t)b * NN + i) * DD + (tid - 224)];
    } else if (tid >= 240) {
        snxi[tid - 240] = nxws[(b * NN + i) * DD + (tid - 240)];
    }
    __syncthreads();

    // ---- sd_ik[i,j]: one thread per j, dense 96-k predicated FMA -----------
    if (tid < NN) {
        u64 mm0 = sm0[tid], mm1 = sm1[tid];
        float s = 0.f;
        #pragma unroll
        for (int k = 0; k < 64; ++k) {
            s += (mm0 & 1) ? sdis[k] : 0.f;
            mm0 >>= 1;
        }
        #pragma unroll
        for (int k = 0; k < 32; ++k) {
            s += (mm1 & 1) ? sdis[64 + k] : 0.f;
            mm1 >>= 1;
        }
        ssdik[tid] = s;
    }
    __syncthreads();

    // ---- msum: each wave covers 24 j's, lane = channel h --------------------
    {
        const int h = (lane < H0D) ? lane : 0;
        float ab = APws[((size_t)b * NN + i) * 128 + h] + b1[h];  // A_i + b1
        const float wij = W1[(3 * DD + 0) * H0D + h];
        const float wjk = W1[(3 * DD + 1) * H0D + h];
        const float wik = W1[(3 * DD + 2) * H0D + h];
        const u64 mi0 = sm0[i], mi1 = sm1[i];
        float ms = 0.f;
        const int j0 = w * 24;
        #pragma unroll
        for (int t = 0; t < 24; ++t) {
            const int j = j0 + t;
            bool e = (j < 64) ? ((mi0 >> j) & 1) : ((mi1 >> (j - 64)) & 1);
            float gP = APws[((size_t)b * NN + j) * 128 + 64 + h];  // unconditional, affine
            float S = sdeg[j] * (ab + sdis[j] * wij) + gP
                    + ssdjk[j] * wjk + ssdik[j] * wik;
            float l = (S >= 0.f) ? S : 0.05f * S;
            ms += e ? l : 0.f;
        }
        if (lane < H0D) smsum[w][lane] = ms;
    }
    __syncthreads();
    if (tid < H0D)
        smsumR[tid] = smsum[0][tid] + smsum[1][tid] + smsum[2][tid] + smsum[3][tid];
    __syncthreads();

    // ---- layer 2 (wave 0, lane = channel) -----------------------------------
    const float degi = sdeg[i], sdjki = ssdjk[i];
    if (w == 0 && lane < H1D) {
        float s = degi * b2[lane];
        #pragma unroll
        for (int d = 0; d < DD; ++d)
            s += degi * sxi[d] * W2[d * H1D + lane]
               + snxi[d] * W2[(DD + d) * H1D + lane];
        s += sdjki * W2[(2 * DD) * H1D + lane];
        for (int c = 0; c < H0D; ++c)
            s += smsumR[c] * W2[(2 * DD + 1 + c) * H1D + lane];
        sm2[lane] = (s >= 0.f) ? s : 0.05f * s;
    }
    __syncthreads();

    // ---- layer 3 + store (wave 0, lane = output channel) --------------------
    if (w == 0) {
        float s = b3[lane];
        #pragma unroll
        for (int d = 0; d < DD; ++d) s += sxi[d] * W3[d * OUTD + lane];
        for (int c = 0; c < H1D; ++c) s += sm2[c] * W3[(DD + c) * OUTD + lane];
        s = (s >= 0.f) ? s : 0.05f * s;
        out[((size_t)b * NN + i) * OUTD + lane] = s;
    }
}

extern "C" void kernel_launch(void* const* d_in, const int* in_sizes, int n_in,
                              void* d_out, int out_size, void* d_ws, size_t ws_size,
                              hipStream_t stream) {
    const float* x   = (const float*)d_in[0];
    const float* adj = (const float*)d_in[1];
    const float* W1  = (const float*)d_in[2];
    const float* b1  = (const float*)d_in[3];
    const float* W2  = (const float*)d_in[4];
    const float* b2  = (const float*)d_in[5];
    const float* W3  = (const float*)d_in[6];
    const float* b3  = (const float*)d_in[7];
    float* out = (float*)d_out;

    // ws layout: masks (u64, 8B-aligned) first, then floats
    u64*   maskws = (u64*)d_ws;                        // 8*96*2 u64 = 12288 B
    float* fbase  = (float*)((char*)d_ws + BB * NN * 2 * sizeof(u64));
    float* disws  = fbase;                             // 8*96*96
    float* degws  = disws + BB * NN * NN;              // 768
    float* sdjkws = degws + BB * NN;                   // 768
    float* nxws   = sdjkws + BB * NN;                  // 8*96*16
    float* APws   = nxws + BB * NN * DD;               // 8*96*128

    kA<<<BB * NN, 64, 0, stream>>>(x, adj, W1, disws, maskws, degws, sdjkws, nxws, APws);
    kB<<<BB * NN, 256, 0, stream>>>(x, W1, b1, W2, b2, W3, b3,
                                    disws, maskws, degws, sdjkws, nxws, APws, out);
}